// Round 1
// baseline (383.214 us; speedup 1.0000x reference)
//
#include <hip/hip_runtime.h>
#include <math.h>

// Problem constants (from reference setup_inputs)
constexpr int Bn = 2, Cn = 256, Hn = 200, Wn = 304, Nroi = 1000;
constexpr int OH = 7, OW = 7, SRn = 2;
constexpr int NS = OH * SRn;   // 14 subsample rows/cols
constexpr int NP = NS * NS;    // 196 subsample positions per roi
constexpr int HWn = Hn * Wn;   // 60800
constexpr float SCALE = 0.25f;

// ---------------------------------------------------------------------------
// Per-position sampling descriptor: base index (y_low*W + x_low), dx (0/1),
// dyW (0/W), and the 4 bilinear weights (zeroed if the sample is "empty").
// Matches the JAX reference arithmetic exactly (f32 throughout).
// ---------------------------------------------------------------------------
__device__ __forceinline__ void compute_desc(const float* __restrict__ r, int p,
                                             int& idx, int& dx, int& dyW,
                                             float4& w) {
  float cw = r[1] * SCALE - 0.5f;
  float ch = r[2] * SCALE - 0.5f;
  float rw = r[3] * SCALE;
  float rh = r[4] * SCALE;
  float theta = r[5] * 0.017453292519943295f;  // pi/180
  float cs = cosf(theta), sn = sinf(theta);
  float bin_h = rh * (1.0f / OH);
  float bin_w = rw * (1.0f / OW);
  int ki = p / NS;
  int kj = p - ki * NS;
  float ty = ((float)ki + 0.5f) * (1.0f / SRn);
  float tx = ((float)kj + 0.5f) * (1.0f / SRn);
  float yy = -0.5f * rh + ty * bin_h;
  float xx = -0.5f * rw + tx * bin_w;
  float y = yy * cs - xx * sn + ch;
  float x = yy * sn + xx * cs + cw;
  bool empty = (y < -1.0f) || (y > (float)Hn) || (x < -1.0f) || (x > (float)Wn);
  y = fmaxf(y, 0.0f);
  x = fmaxf(x, 0.0f);
  int yl = min(max((int)floorf(y), 0), Hn - 1);
  int xl = min(max((int)floorf(x), 0), Wn - 1);
  int yh = min(yl + 1, Hn - 1);
  int xh = min(xl + 1, Wn - 1);
  float ly = fminf(fmaxf(y - (float)yl, 0.0f), 1.0f);
  float lx = fminf(fmaxf(x - (float)xl, 0.0f), 1.0f);
  float hy = 1.0f - ly, hx = 1.0f - lx;
  if (empty) {
    w.x = w.y = w.z = w.w = 0.0f;
  } else {
    w.x = hy * hx;  // (y_low , x_low )
    w.y = hy * lx;  // (y_low , x_high)
    w.z = ly * hx;  // (y_high, x_low )
    w.w = ly * lx;  // (y_high, x_high)
  }
  idx = yl * Wn + xl;
  dx = xh - xl;
  dyW = (yh - yl) * Wn;
}

// ---------------------------------------------------------------------------
// Kernel 1: transpose feats (B,C,H*W) -> ft (B,H*W,C). Tiled through LDS so
// both global read and write are coalesced. P=60800 = 32*1900, C=256 = 32*8.
// ---------------------------------------------------------------------------
constexpr int TP = 32, TC = 32;
__global__ __launch_bounds__(256) void transpose_k(const float* __restrict__ feats,
                                                   float* __restrict__ ft) {
  __shared__ float tile[TC][TP + 1];
  int p0 = blockIdx.x * TP;
  int c0 = blockIdx.y * TC;
  int b = blockIdx.z;
  int t = threadIdx.x;
  int tx = t % TP;      // pixel within tile
  int ty0 = t / TP;     // 0..7
#pragma unroll
  for (int i = 0; i < TC; i += 8) {
    int c = c0 + ty0 + i;
    tile[ty0 + i][tx] = feats[((size_t)b * Cn + c) * HWn + p0 + tx];
  }
  __syncthreads();
  int cx = t % TC;      // channel within tile
  int py0 = t / TC;     // 0..7
#pragma unroll
  for (int j = 0; j < TP; j += 8) {
    int p = p0 + py0 + j;
    ft[((size_t)b * HWn + p) * Cn + c0 + cx] = tile[cx][py0 + j];
  }
}

// ---------------------------------------------------------------------------
// Kernel 2 (fast path): gather from transposed ft. One block per roi.
// Lane l of each wave handles channels 4l..4l+3 via float4 (fully coalesced:
// 64 lanes x 16 B = 1 KiB per corner). The 4 waves split the 49 output bins.
// ---------------------------------------------------------------------------
__global__ __launch_bounds__(256) void roi_gather_t(const float* __restrict__ ft,
                                                    const float* __restrict__ rois,
                                                    float* __restrict__ out) {
  __shared__ int s_idx[NP];
  __shared__ int s_dx[NP];
  __shared__ int s_dy[NP];
  __shared__ float4 s_w[NP];
  int n = blockIdx.x;
  const float* r = rois + (size_t)n * 6;
  int t = threadIdx.x;
  if (t < NP) {
    int idx, dx, dy;
    float4 w;
    compute_desc(r, t, idx, dx, dy, w);
    s_idx[t] = idx;
    s_dx[t] = dx;
    s_dy[t] = dy;
    s_w[t] = w;
  }
  __syncthreads();
  int b = (int)r[0];
  int lane = t & 63;   // channel group: channels 4*lane .. 4*lane+3
  int wv = t >> 6;     // wave id 0..3
  const float4* fb = (const float4*)(ft + (size_t)b * HWn * Cn);
  float* o = out + (size_t)n * Cn * (OH * OW);
  for (int bin = wv; bin < OH * OW; bin += 4) {
    int bi = bin / OW;
    int bj = bin - bi * OW;
    float4 acc = {0.0f, 0.0f, 0.0f, 0.0f};
#pragma unroll
    for (int s = 0; s < 4; ++s) {
      int ki = bi * 2 + (s >> 1);
      int kj = bj * 2 + (s & 1);
      int p = ki * NS + kj;
      int idx = s_idx[p];
      int dx = s_dx[p];
      int dy = s_dy[p];
      float4 w = s_w[p];
      float4 v1 = fb[(size_t)idx * 64 + lane];
      float4 v2 = fb[(size_t)(idx + dx) * 64 + lane];
      float4 v3 = fb[(size_t)(idx + dy) * 64 + lane];
      float4 v4 = fb[(size_t)(idx + dy + dx) * 64 + lane];
      acc.x += w.x * v1.x + w.y * v2.x + w.z * v3.x + w.w * v4.x;
      acc.y += w.x * v1.y + w.y * v2.y + w.z * v3.y + w.w * v4.y;
      acc.z += w.x * v1.z + w.y * v2.z + w.z * v3.z + w.w * v4.z;
      acc.w += w.x * v1.w + w.y * v2.w + w.z * v3.w + w.w * v4.w;
    }
    int c = lane * 4;
    o[(size_t)(c + 0) * 49 + bin] = acc.x * 0.25f;
    o[(size_t)(c + 1) * 49 + bin] = acc.y * 0.25f;
    o[(size_t)(c + 2) * 49 + bin] = acc.z * 0.25f;
    o[(size_t)(c + 3) * 49 + bin] = acc.w * 0.25f;
  }
}

// ---------------------------------------------------------------------------
// Fallback (if workspace too small): direct gather from (B,C,H,W).
// One block per roi, one thread per channel. Uncoalesced but correct.
// ---------------------------------------------------------------------------
__global__ __launch_bounds__(256) void roi_direct(const float* __restrict__ feats,
                                                  const float* __restrict__ rois,
                                                  float* __restrict__ out) {
  __shared__ int s_idx[NP];
  __shared__ int s_dx[NP];
  __shared__ int s_dy[NP];
  __shared__ float4 s_w[NP];
  int n = blockIdx.x;
  const float* r = rois + (size_t)n * 6;
  int t = threadIdx.x;
  if (t < NP) {
    int idx, dx, dy;
    float4 w;
    compute_desc(r, t, idx, dx, dy, w);
    s_idx[t] = idx;
    s_dx[t] = dx;
    s_dy[t] = dy;
    s_w[t] = w;
  }
  __syncthreads();
  int b = (int)r[0];
  const float* f = feats + ((size_t)b * Cn + t) * HWn;
  float* o = out + ((size_t)n * Cn + t) * (OH * OW);
  for (int bi = 0; bi < OH; ++bi) {
    for (int bj = 0; bj < OW; ++bj) {
      float acc = 0.0f;
#pragma unroll
      for (int s = 0; s < 4; ++s) {
        int ki = bi * 2 + (s >> 1);
        int kj = bj * 2 + (s & 1);
        int p = ki * NS + kj;
        int idx = s_idx[p];
        int dx = s_dx[p];
        int dy = s_dy[p];
        float4 w = s_w[p];
        float v1 = f[idx];
        float v2 = f[idx + dx];
        float v3 = f[idx + dy];
        float v4 = f[idx + dy + dx];
        acc += w.x * v1 + w.y * v2 + w.z * v3 + w.w * v4;
      }
      o[bi * OW + bj] = acc * 0.25f;
    }
  }
}

extern "C" void kernel_launch(void* const* d_in, const int* in_sizes, int n_in,
                              void* d_out, int out_size, void* d_ws, size_t ws_size,
                              hipStream_t stream) {
  const float* feats = (const float*)d_in[0];  // (2,256,200,304) f32
  const float* rois = (const float*)d_in[1];   // (1000,6) f32
  float* out = (float*)d_out;                  // (1000,256,7,7) f32

  size_t need = (size_t)Bn * HWn * Cn * sizeof(float);  // ~124.6 MB
  if (ws_size >= need) {
    float* ft = (float*)d_ws;
    transpose_k<<<dim3(HWn / TP, Cn / TC, Bn), 256, 0, stream>>>(feats, ft);
    roi_gather_t<<<Nroi, 256, 0, stream>>>(ft, rois, out);
  } else {
    roi_direct<<<Nroi, 256, 0, stream>>>(feats, rois, out);
  }
}

// Round 2
// 340.473 us; speedup vs baseline: 1.1255x; 1.1255x over previous
//
#include <hip/hip_runtime.h>
#include <math.h>

// Problem constants (from reference setup_inputs)
constexpr int Bn = 2, Cn = 256, Hn = 200, Wn = 304, Nroi = 1000;
constexpr int OH = 7, OW = 7, SRn = 2;
constexpr int NS = OH * SRn;   // 14 subsample rows/cols
constexpr int NP = NS * NS;    // 196 subsample positions per roi
constexpr int NBIN = OH * OW;  // 49
constexpr int HWn = Hn * Wn;   // 60800
constexpr float SCALE = 0.25f;

// ---------------------------------------------------------------------------
// Per-position sampling descriptor: base index (y_low*W + x_low), dx (0/1),
// dyW (0/W), and the 4 bilinear weights (zeroed if the sample is "empty").
// Matches the JAX reference arithmetic exactly (f32 throughout).
// ---------------------------------------------------------------------------
__device__ __forceinline__ void compute_desc(const float* __restrict__ r, int p,
                                             int& idx, int& dx, int& dyW,
                                             float4& w) {
  float cw = r[1] * SCALE - 0.5f;
  float ch = r[2] * SCALE - 0.5f;
  float rw = r[3] * SCALE;
  float rh = r[4] * SCALE;
  float theta = r[5] * 0.017453292519943295f;  // pi/180
  float cs = cosf(theta), sn = sinf(theta);
  float bin_h = rh * (1.0f / OH);
  float bin_w = rw * (1.0f / OW);
  int ki = p / NS;
  int kj = p - ki * NS;
  float ty = ((float)ki + 0.5f) * (1.0f / SRn);
  float tx = ((float)kj + 0.5f) * (1.0f / SRn);
  float yy = -0.5f * rh + ty * bin_h;
  float xx = -0.5f * rw + tx * bin_w;
  float y = yy * cs - xx * sn + ch;
  float x = yy * sn + xx * cs + cw;
  bool empty = (y < -1.0f) || (y > (float)Hn) || (x < -1.0f) || (x > (float)Wn);
  y = fmaxf(y, 0.0f);
  x = fmaxf(x, 0.0f);
  int yl = min(max((int)floorf(y), 0), Hn - 1);
  int xl = min(max((int)floorf(x), 0), Wn - 1);
  int yh = min(yl + 1, Hn - 1);
  int xh = min(xl + 1, Wn - 1);
  float ly = fminf(fmaxf(y - (float)yl, 0.0f), 1.0f);
  float lx = fminf(fmaxf(x - (float)xl, 0.0f), 1.0f);
  float hy = 1.0f - ly, hx = 1.0f - lx;
  if (empty) {
    w.x = w.y = w.z = w.w = 0.0f;
  } else {
    w.x = hy * hx;  // (y_low , x_low )
    w.y = hy * lx;  // (y_low , x_high)
    w.z = ly * hx;  // (y_high, x_low )
    w.w = ly * lx;  // (y_high, x_high)
  }
  idx = yl * Wn + xl;
  dx = xh - xl;
  dyW = (yh - yl) * Wn;
}

// ---------------------------------------------------------------------------
// Kernel 1 v2: transpose feats (B,C,P) -> ft (B,P,C), 64px x 64ch tiles.
// float4 on BOTH global sides (4 consecutive px on read, 4 consecutive ch on
// write); LDS staged scalar with +1-pad rows (worst 2-way conflict = free).
// ---------------------------------------------------------------------------
constexpr int TPX = 64, TCH = 64, LP = TPX + 1;
__global__ __launch_bounds__(256) void transpose2(const float* __restrict__ feats,
                                                  float* __restrict__ ft) {
  __shared__ float tile[TCH * LP];
  int p0 = blockIdx.x * TPX;  // 60800/64 = 950
  int c0 = blockIdx.y * TCH;  // 256/64  = 4
  int b = blockIdx.z;
  int t = threadIdx.x;
  int px4 = t & 15, ch = t >> 4;  // read mapping: 16 float4 across pixels
#pragma unroll
  for (int i = 0; i < 4; ++i) {
    int c = ch + 16 * i;
    const float4 v = *(const float4*)(feats + ((size_t)b * Cn + c0 + c) * HWn + p0 + px4 * 4);
    tile[c * LP + px4 * 4 + 0] = v.x;
    tile[c * LP + px4 * 4 + 1] = v.y;
    tile[c * LP + px4 * 4 + 2] = v.z;
    tile[c * LP + px4 * 4 + 3] = v.w;
  }
  __syncthreads();
  int ch4 = t & 15, px = t >> 4;  // write mapping: 16 float4 across channels
#pragma unroll
  for (int i = 0; i < 4; ++i) {
    int p = px + 16 * i;
    float4 v;
    v.x = tile[(ch4 * 4 + 0) * LP + p];
    v.y = tile[(ch4 * 4 + 1) * LP + p];
    v.z = tile[(ch4 * 4 + 2) * LP + p];
    v.w = tile[(ch4 * 4 + 3) * LP + p];
    *(float4*)(ft + ((size_t)b * HWn + p0 + p) * Cn + c0 + ch4 * 4) = v;
  }
}

// ---------------------------------------------------------------------------
// Kernel 2 v2: gather from transposed ft.
// block = (roi, channel-group of 64). lane = channel within group (256 B
// coalesced loads per wave), wave w handles bins w, w+4, ... Each block owns
// a CONTIGUOUS 64ch x 49bin = 12.5 KB output region -> cache lines are fully
// covered by one CU (kills the 4x write amplification). Grid = 4000 blocks
// = 16000 waves -> occupancy no longer grid-capped.
// ---------------------------------------------------------------------------
__global__ __launch_bounds__(256) void roi_gather2(const float* __restrict__ ft,
                                                   const float* __restrict__ rois,
                                                   float* __restrict__ out) {
  __shared__ int s_idx[NP];
  __shared__ int s_dx[NP];
  __shared__ int s_dy[NP];
  __shared__ float4 s_w[NP];
  int n = blockIdx.x;
  int cg = blockIdx.y;  // channel group 0..3 (64 channels each)
  const float* r = rois + (size_t)n * 6;
  int t = threadIdx.x;
  if (t < NP) {
    int idx, dx, dy;
    float4 w;
    compute_desc(r, t, idx, dx, dy, w);
    s_idx[t] = idx;
    s_dx[t] = dx;
    s_dy[t] = dy;
    s_w[t] = w;
  }
  __syncthreads();
  int b = (int)r[0];
  int lane = t & 63;  // channel within group
  int wv = t >> 6;    // wave id 0..3 -> bin subset
  const float* fb = ft + (size_t)b * HWn * Cn + cg * 64 + lane;
  float* o = out + (size_t)n * Cn * NBIN + (size_t)(cg * 64 + lane) * NBIN;
  for (int bin = wv; bin < NBIN; bin += 4) {
    int bi = bin / OW;
    int bj = bin - bi * OW;
    float acc = 0.0f;
#pragma unroll
    for (int s = 0; s < 4; ++s) {
      int p = (bi * 2 + (s >> 1)) * NS + bj * 2 + (s & 1);
      int idx = s_idx[p];  // broadcast (all lanes same p) - conflict-free
      int dx = s_dx[p];
      int dy = s_dy[p];
      float4 w = s_w[p];
      float v1 = fb[(size_t)idx * Cn];
      float v2 = fb[(size_t)(idx + dx) * Cn];
      float v3 = fb[(size_t)(idx + dy) * Cn];
      float v4 = fb[(size_t)(idx + dy + dx) * Cn];
      acc += w.x * v1 + w.y * v2 + w.z * v3 + w.w * v4;
    }
    o[bin] = acc * 0.25f;
  }
}

// ---------------------------------------------------------------------------
// Fallback (if workspace too small): direct gather from (B,C,H,W).
// ---------------------------------------------------------------------------
__global__ __launch_bounds__(256) void roi_direct(const float* __restrict__ feats,
                                                  const float* __restrict__ rois,
                                                  float* __restrict__ out) {
  __shared__ int s_idx[NP];
  __shared__ int s_dx[NP];
  __shared__ int s_dy[NP];
  __shared__ float4 s_w[NP];
  int n = blockIdx.x;
  const float* r = rois + (size_t)n * 6;
  int t = threadIdx.x;
  if (t < NP) {
    int idx, dx, dy;
    float4 w;
    compute_desc(r, t, idx, dx, dy, w);
    s_idx[t] = idx;
    s_dx[t] = dx;
    s_dy[t] = dy;
    s_w[t] = w;
  }
  __syncthreads();
  int b = (int)r[0];
  const float* f = feats + ((size_t)b * Cn + t) * HWn;
  float* o = out + ((size_t)n * Cn + t) * NBIN;
  for (int bi = 0; bi < OH; ++bi) {
    for (int bj = 0; bj < OW; ++bj) {
      float acc = 0.0f;
#pragma unroll
      for (int s = 0; s < 4; ++s) {
        int p = (bi * 2 + (s >> 1)) * NS + bj * 2 + (s & 1);
        int idx = s_idx[p];
        int dx = s_dx[p];
        int dy = s_dy[p];
        float4 w = s_w[p];
        acc += w.x * f[idx] + w.y * f[idx + dx] + w.z * f[idx + dy] + w.w * f[idx + dy + dx];
      }
      o[bi * OW + bj] = acc * 0.25f;
    }
  }
}

extern "C" void kernel_launch(void* const* d_in, const int* in_sizes, int n_in,
                              void* d_out, int out_size, void* d_ws, size_t ws_size,
                              hipStream_t stream) {
  const float* feats = (const float*)d_in[0];  // (2,256,200,304) f32
  const float* rois = (const float*)d_in[1];   // (1000,6) f32
  float* out = (float*)d_out;                  // (1000,256,7,7) f32

  size_t need = (size_t)Bn * HWn * Cn * sizeof(float);  // ~124.6 MB
  if (ws_size >= need) {
    float* ft = (float*)d_ws;
    transpose2<<<dim3(HWn / TPX, Cn / TCH, Bn), 256, 0, stream>>>(feats, ft);
    roi_gather2<<<dim3(Nroi, Cn / 64), 256, 0, stream>>>(ft, rois, out);
  } else {
    roi_direct<<<Nroi, 256, 0, stream>>>(feats, rois, out);
  }
}

// Round 4
// 288.200 us; speedup vs baseline: 1.3297x; 1.1814x over previous
//
#include <hip/hip_runtime.h>
#include <math.h>

// Problem constants (from reference setup_inputs)
constexpr int Bn = 2, Cn = 256, Hn = 200, Wn = 304, Nroi = 1000;
constexpr int OH = 7, OW = 7, SRn = 2;
constexpr int NS = OH * SRn;   // 14 subsample rows/cols
constexpr int NP = NS * NS;    // 196 subsample positions per roi
constexpr int NBIN = OH * OW;  // 49
constexpr int HWn = Hn * Wn;   // 60800
constexpr float SCALE = 0.25f;

// ---------------------------------------------------------------------------
// Per-position sampling descriptor (matches JAX reference arithmetic, f32).
// ---------------------------------------------------------------------------
__device__ __forceinline__ void compute_desc(const float* __restrict__ r, int p,
                                             int& idx, int& dx, int& dyW,
                                             float4& w) {
  float cw = r[1] * SCALE - 0.5f;
  float ch = r[2] * SCALE - 0.5f;
  float rw = r[3] * SCALE;
  float rh = r[4] * SCALE;
  float theta = r[5] * 0.017453292519943295f;  // pi/180
  float cs = cosf(theta), sn = sinf(theta);
  float bin_h = rh * (1.0f / OH);
  float bin_w = rw * (1.0f / OW);
  int ki = p / NS;
  int kj = p - ki * NS;
  float ty = ((float)ki + 0.5f) * (1.0f / SRn);
  float tx = ((float)kj + 0.5f) * (1.0f / SRn);
  float yy = -0.5f * rh + ty * bin_h;
  float xx = -0.5f * rw + tx * bin_w;
  float y = yy * cs - xx * sn + ch;
  float x = yy * sn + xx * cs + cw;
  bool empty = (y < -1.0f) || (y > (float)Hn) || (x < -1.0f) || (x > (float)Wn);
  y = fmaxf(y, 0.0f);
  x = fmaxf(x, 0.0f);
  int yl = min(max((int)floorf(y), 0), Hn - 1);
  int xl = min(max((int)floorf(x), 0), Wn - 1);
  int yh = min(yl + 1, Hn - 1);
  int xh = min(xl + 1, Wn - 1);
  float ly = fminf(fmaxf(y - (float)yl, 0.0f), 1.0f);
  float lx = fminf(fmaxf(x - (float)xl, 0.0f), 1.0f);
  float hy = 1.0f - ly, hx = 1.0f - lx;
  if (empty) {
    w.x = w.y = w.z = w.w = 0.0f;
  } else {
    w.x = hy * hx;
    w.y = hy * lx;
    w.z = ly * hx;
    w.w = ly * lx;
  }
  idx = yl * Wn + xl;
  dx = xh - xl;
  dyW = (yh - yl) * Wn;
}

// ---------------------------------------------------------------------------
// Kernel 1: transpose feats (B,C,P) -> ft (B,P,C), 64px x 64ch tiles.
// ---------------------------------------------------------------------------
constexpr int TPX = 64, TCH = 64, LP = TPX + 1;
__global__ __launch_bounds__(256) void transpose2(const float* __restrict__ feats,
                                                  float* __restrict__ ft) {
  __shared__ float tile[TCH * LP];
  int p0 = blockIdx.x * TPX;
  int c0 = blockIdx.y * TCH;
  int b = blockIdx.z;
  int t = threadIdx.x;
  int px4 = t & 15, ch = t >> 4;
#pragma unroll
  for (int i = 0; i < 4; ++i) {
    int c = ch + 16 * i;
    const float4 v = *(const float4*)(feats + ((size_t)b * Cn + c0 + c) * HWn + p0 + px4 * 4);
    tile[c * LP + px4 * 4 + 0] = v.x;
    tile[c * LP + px4 * 4 + 1] = v.y;
    tile[c * LP + px4 * 4 + 2] = v.z;
    tile[c * LP + px4 * 4 + 3] = v.w;
  }
  __syncthreads();
  int ch4 = t & 15, px = t >> 4;
#pragma unroll
  for (int i = 0; i < 4; ++i) {
    int p = px + 16 * i;
    float4 v;
    v.x = tile[(ch4 * 4 + 0) * LP + p];
    v.y = tile[(ch4 * 4 + 1) * LP + p];
    v.z = tile[(ch4 * 4 + 2) * LP + p];
    v.w = tile[(ch4 * 4 + 3) * LP + p];
    *(float4*)(ft + ((size_t)b * HWn + p0 + p) * Cn + c0 + ch4 * 4) = v;
  }
}

// ---------------------------------------------------------------------------
// Kernel 2 v3b: gather from transposed ft with LDS-staged output.
// block = (roi, channel-group of 64); lane = channel (256 B coalesced loads),
// wave w handles bins w, w+4, ... Results go to an LDS tile (lane*49+bin:
// for a fixed bin the 64 lanes map 17*lane mod 32 -> all banks, 2-way = free),
// then one barrier and a contiguous float4 write pass: every store
// instruction covers 4 full cache lines.
// R3 BUG FIXED: the tile is 3136 floats = 784 float4 (NOT 3136 float4);
// the old loop read 4x past s_out and stomped 3 neighbor blocks' output.
// ---------------------------------------------------------------------------
__global__ __launch_bounds__(256) void roi_gather3(const float* __restrict__ ft,
                                                   const float* __restrict__ rois,
                                                   float* __restrict__ out) {
  __shared__ int s_idx[NP];
  __shared__ int s_dx[NP];
  __shared__ int s_dy[NP];
  __shared__ float4 s_w[NP];
  __shared__ __align__(16) float s_out[64 * NBIN];  // 3136 floats = 784 float4
  int n = blockIdx.x;
  int cg = blockIdx.y;  // channel group 0..3 (64 channels each)
  const float* r = rois + (size_t)n * 6;
  int t = threadIdx.x;
  if (t < NP) {
    int idx, dx, dy;
    float4 w;
    compute_desc(r, t, idx, dx, dy, w);
    s_idx[t] = idx;
    s_dx[t] = dx;
    s_dy[t] = dy;
    s_w[t] = w;
  }
  __syncthreads();
  int b = (int)r[0];
  int lane = t & 63;  // channel within group
  int wv = t >> 6;    // wave id 0..3 -> bin subset
  const float* fb = ft + (size_t)b * HWn * Cn + cg * 64 + lane;
  for (int bin = wv; bin < NBIN; bin += 4) {
    int bi = bin / OW;
    int bj = bin - bi * OW;
    float acc = 0.0f;
#pragma unroll
    for (int s = 0; s < 4; ++s) {
      int p = (bi * 2 + (s >> 1)) * NS + bj * 2 + (s & 1);
      int idx = s_idx[p];  // broadcast (all lanes same p)
      int dx = s_dx[p];
      int dy = s_dy[p];
      float4 w = s_w[p];
      float v1 = fb[(size_t)idx * Cn];
      float v2 = fb[(size_t)(idx + dx) * Cn];
      float v3 = fb[(size_t)(idx + dy) * Cn];
      float v4 = fb[(size_t)(idx + dy + dx) * Cn];
      acc += w.x * v1 + w.y * v2 + w.z * v3 + w.w * v4;
    }
    s_out[lane * NBIN + bin] = acc * 0.25f;
  }
  __syncthreads();
  // Contiguous coalesced write-out: 64ch x 49bin = 3136 floats = 784 float4.
  const float4* s4 = (const float4*)s_out;
  float4* o4 = (float4*)(out + (size_t)n * Cn * NBIN + (size_t)cg * 64 * NBIN);
#pragma unroll
  for (int k = 0; k < 3; ++k) {
    o4[t + 256 * k] = s4[t + 256 * k];
  }
  if (t < 784 - 3 * 256) {
    o4[t + 256 * 3] = s4[t + 256 * 3];
  }
}

// ---------------------------------------------------------------------------
// Fallback (if workspace too small): direct gather from (B,C,H,W).
// ---------------------------------------------------------------------------
__global__ __launch_bounds__(256) void roi_direct(const float* __restrict__ feats,
                                                  const float* __restrict__ rois,
                                                  float* __restrict__ out) {
  __shared__ int s_idx[NP];
  __shared__ int s_dx[NP];
  __shared__ int s_dy[NP];
  __shared__ float4 s_w[NP];
  int n = blockIdx.x;
  const float* r = rois + (size_t)n * 6;
  int t = threadIdx.x;
  if (t < NP) {
    int idx, dx, dy;
    float4 w;
    compute_desc(r, t, idx, dx, dy, w);
    s_idx[t] = idx;
    s_dx[t] = dx;
    s_dy[t] = dy;
    s_w[t] = w;
  }
  __syncthreads();
  int b = (int)r[0];
  const float* f = feats + ((size_t)b * Cn + t) * HWn;
  float* o = out + ((size_t)n * Cn + t) * NBIN;
  for (int bi = 0; bi < OH; ++bi) {
    for (int bj = 0; bj < OW; ++bj) {
      float acc = 0.0f;
#pragma unroll
      for (int s = 0; s < 4; ++s) {
        int p = (bi * 2 + (s >> 1)) * NS + bj * 2 + (s & 1);
        int idx = s_idx[p];
        int dx = s_dx[p];
        int dy = s_dy[p];
        float4 w = s_w[p];
        acc += w.x * f[idx] + w.y * f[idx + dx] + w.z * f[idx + dy] + w.w * f[idx + dy + dx];
      }
      o[bi * OW + bj] = acc * 0.25f;
    }
  }
}

extern "C" void kernel_launch(void* const* d_in, const int* in_sizes, int n_in,
                              void* d_out, int out_size, void* d_ws, size_t ws_size,
                              hipStream_t stream) {
  const float* feats = (const float*)d_in[0];  // (2,256,200,304) f32
  const float* rois = (const float*)d_in[1];   // (1000,6) f32
  float* out = (float*)d_out;                  // (1000,256,7,7) f32

  size_t need = (size_t)Bn * HWn * Cn * sizeof(float);  // ~124.6 MB
  if (ws_size >= need) {
    float* ft = (float*)d_ws;
    transpose2<<<dim3(HWn / TPX, Cn / TCH, Bn), 256, 0, stream>>>(feats, ft);
    roi_gather3<<<dim3(Nroi, Cn / 64), 256, 0, stream>>>(ft, rois, out);
  } else {
    roi_direct<<<Nroi, 256, 0, stream>>>(feats, rois, out);
  }
}

// Round 5
// 282.193 us; speedup vs baseline: 1.3580x; 1.0213x over previous
//
#include <hip/hip_runtime.h>
#include <math.h>

// Problem constants (from reference setup_inputs)
constexpr int Bn = 2, Cn = 256, Hn = 200, Wn = 304, Nroi = 1000;
constexpr int OH = 7, OW = 7, SRn = 2;
constexpr int NS = OH * SRn;   // 14 subsample rows/cols
constexpr int NP = NS * NS;    // 196 subsample positions per roi
constexpr int NBIN = OH * OW;  // 49
constexpr int HWn = Hn * Wn;   // 60800
constexpr float SCALE = 0.25f;

// ---------------------------------------------------------------------------
// Per-position sampling descriptor (matches JAX reference arithmetic, f32).
// ---------------------------------------------------------------------------
__device__ __forceinline__ void compute_desc(const float* __restrict__ r, int p,
                                             int& idx, int& dx, int& dyW,
                                             float4& w) {
  float cw = r[1] * SCALE - 0.5f;
  float ch = r[2] * SCALE - 0.5f;
  float rw = r[3] * SCALE;
  float rh = r[4] * SCALE;
  float theta = r[5] * 0.017453292519943295f;  // pi/180
  float cs = cosf(theta), sn = sinf(theta);
  float bin_h = rh * (1.0f / OH);
  float bin_w = rw * (1.0f / OW);
  int ki = p / NS;
  int kj = p - ki * NS;
  float ty = ((float)ki + 0.5f) * (1.0f / SRn);
  float tx = ((float)kj + 0.5f) * (1.0f / SRn);
  float yy = -0.5f * rh + ty * bin_h;
  float xx = -0.5f * rw + tx * bin_w;
  float y = yy * cs - xx * sn + ch;
  float x = yy * sn + xx * cs + cw;
  bool empty = (y < -1.0f) || (y > (float)Hn) || (x < -1.0f) || (x > (float)Wn);
  y = fmaxf(y, 0.0f);
  x = fmaxf(x, 0.0f);
  int yl = min(max((int)floorf(y), 0), Hn - 1);
  int xl = min(max((int)floorf(x), 0), Wn - 1);
  int yh = min(yl + 1, Hn - 1);
  int xh = min(xl + 1, Wn - 1);
  float ly = fminf(fmaxf(y - (float)yl, 0.0f), 1.0f);
  float lx = fminf(fmaxf(x - (float)xl, 0.0f), 1.0f);
  float hy = 1.0f - ly, hx = 1.0f - lx;
  if (empty) {
    w.x = w.y = w.z = w.w = 0.0f;
  } else {
    w.x = hy * hx;
    w.y = hy * lx;
    w.z = ly * hx;
    w.w = ly * lx;
  }
  idx = yl * Wn + xl;
  dx = xh - xl;
  dyW = (yh - yl) * Wn;
}

// ---------------------------------------------------------------------------
// Kernel 1: transpose feats (B,C,P) -> ft (B,P,C), 64px x 64ch tiles.
// (unchanged — BW-bound; kept stable for attribution)
// ---------------------------------------------------------------------------
constexpr int TPX = 64, TCH = 64, LP = TPX + 1;
__global__ __launch_bounds__(256) void transpose2(const float* __restrict__ feats,
                                                  float* __restrict__ ft) {
  __shared__ float tile[TCH * LP];
  int p0 = blockIdx.x * TPX;
  int c0 = blockIdx.y * TCH;
  int b = blockIdx.z;
  int t = threadIdx.x;
  int px4 = t & 15, ch = t >> 4;
#pragma unroll
  for (int i = 0; i < 4; ++i) {
    int c = ch + 16 * i;
    const float4 v = *(const float4*)(feats + ((size_t)b * Cn + c0 + c) * HWn + p0 + px4 * 4);
    tile[c * LP + px4 * 4 + 0] = v.x;
    tile[c * LP + px4 * 4 + 1] = v.y;
    tile[c * LP + px4 * 4 + 2] = v.z;
    tile[c * LP + px4 * 4 + 3] = v.w;
  }
  __syncthreads();
  int ch4 = t & 15, px = t >> 4;
#pragma unroll
  for (int i = 0; i < 4; ++i) {
    int p = px + 16 * i;
    float4 v;
    v.x = tile[(ch4 * 4 + 0) * LP + p];
    v.y = tile[(ch4 * 4 + 1) * LP + p];
    v.z = tile[(ch4 * 4 + 2) * LP + p];
    v.w = tile[(ch4 * 4 + 3) * LP + p];
    *(float4*)(ft + ((size_t)b * HWn + p0 + p) * Cn + c0 + ch4 * 4) = v;
  }
}

// ---------------------------------------------------------------------------
// Kernel 2 v4: float4-vectorized gather, no cross-lane reduce.
// block = (roi, channel-group of 64), 256 threads = 4 waves.
// Wave lane map: q = lane&15 (channel quad -> 4 consecutive channels),
//                g = lane>>4 (bin within the wave's 4-bin pack).
// Iteration `it` covers bins it*16 + wv*4 + g (3 full passes + bin-48 tail).
// Samples s=0..3 run SEQUENTIALLY per lane, so each lane accumulates its
// complete bin value for its 4 channels in registers -> no shuffles.
// Each global load is dwordx4: 4 bin-groups x 16 lanes x 16 B = 4x256 B
// contiguous chunks -> 4x fewer VMEM instructions and ~6x less addr VALU
// than v3 (descriptors pre-packed as BYTE offsets).
// LDS result stores: component j -> s_out[(q*4+j)*49+bin]; bank =
// (4q+17j+bin) mod 32 = exactly 2 lanes/bank = free.
// ---------------------------------------------------------------------------
__global__ __launch_bounds__(256) void roi_gather4(const float* __restrict__ ft,
                                                   const float* __restrict__ rois,
                                                   float* __restrict__ out) {
  __shared__ int4 s_m[NP];   // {idx*1024, dx*1024, dy*1024, 0} byte offsets
  __shared__ float4 s_w[NP];
  __shared__ __align__(16) float s_out[64 * NBIN];  // 3136 floats = 784 float4
  int n = blockIdx.x;
  int cg = blockIdx.y;  // channel group 0..3 (64 channels each)
  const float* r = rois + (size_t)n * 6;
  int t = threadIdx.x;
  if (t < NP) {
    int idx, dx, dy;
    float4 w;
    compute_desc(r, t, idx, dx, dy, w);
    s_m[t] = make_int4(idx * (Cn * 4), dx * (Cn * 4), dy * (Cn * 4), 0);
    s_w[t] = w;
  }
  __syncthreads();
  int b = (int)r[0];
  int lane = t & 63;
  int wv = t >> 6;
  int q = lane & 15;   // channel quad
  int g = lane >> 4;   // bin group 0..3
  const char* fb = (const char*)(ft + (size_t)b * HWn * Cn + cg * 64) + q * 16;
#pragma unroll
  for (int it = 0; it < 4; ++it) {
    int bin = it * 16 + wv * 4 + g;
    if (bin < NBIN) {
      int bi = bin / OW;
      int bj = bin - bi * OW;
      float4 acc = {0.0f, 0.0f, 0.0f, 0.0f};
#pragma unroll
      for (int s = 0; s < 4; ++s) {
        int p = (bi * 2 + (s >> 1)) * NS + bj * 2 + (s & 1);
        int4 m = s_m[p];      // 16-lane broadcast, 4 distinct addrs/wave
        float4 w = s_w[p];
        const char* base = fb + m.x;
        float4 v1 = *(const float4*)(base);
        float4 v2 = *(const float4*)(base + m.y);
        float4 v3 = *(const float4*)(base + m.z);
        float4 v4 = *(const float4*)(base + m.z + m.y);
        acc.x += w.x * v1.x + w.y * v2.x + w.z * v3.x + w.w * v4.x;
        acc.y += w.x * v1.y + w.y * v2.y + w.z * v3.y + w.w * v4.y;
        acc.z += w.x * v1.z + w.y * v2.z + w.z * v3.z + w.w * v4.z;
        acc.w += w.x * v1.w + w.y * v2.w + w.z * v3.w + w.w * v4.w;
      }
      s_out[(q * 4 + 0) * NBIN + bin] = acc.x * 0.25f;
      s_out[(q * 4 + 1) * NBIN + bin] = acc.y * 0.25f;
      s_out[(q * 4 + 2) * NBIN + bin] = acc.z * 0.25f;
      s_out[(q * 4 + 3) * NBIN + bin] = acc.w * 0.25f;
    }
  }
  __syncthreads();
  // Contiguous coalesced write-out: 64ch x 49bin = 3136 floats = 784 float4.
  const float4* s4 = (const float4*)s_out;
  float4* o4 = (float4*)(out + (size_t)n * Cn * NBIN + (size_t)cg * 64 * NBIN);
#pragma unroll
  for (int k = 0; k < 3; ++k) {
    o4[t + 256 * k] = s4[t + 256 * k];
  }
  if (t < 784 - 3 * 256) {
    o4[t + 256 * 3] = s4[t + 256 * 3];
  }
}

// ---------------------------------------------------------------------------
// Fallback (if workspace too small): direct gather from (B,C,H,W).
// ---------------------------------------------------------------------------
__global__ __launch_bounds__(256) void roi_direct(const float* __restrict__ feats,
                                                  const float* __restrict__ rois,
                                                  float* __restrict__ out) {
  __shared__ int s_idx[NP];
  __shared__ int s_dx[NP];
  __shared__ int s_dy[NP];
  __shared__ float4 s_w[NP];
  int n = blockIdx.x;
  const float* r = rois + (size_t)n * 6;
  int t = threadIdx.x;
  if (t < NP) {
    int idx, dx, dy;
    float4 w;
    compute_desc(r, t, idx, dx, dy, w);
    s_idx[t] = idx;
    s_dx[t] = dx;
    s_dy[t] = dy;
    s_w[t] = w;
  }
  __syncthreads();
  int b = (int)r[0];
  const float* f = feats + ((size_t)b * Cn + t) * HWn;
  float* o = out + ((size_t)n * Cn + t) * NBIN;
  for (int bi = 0; bi < OH; ++bi) {
    for (int bj = 0; bj < OW; ++bj) {
      float acc = 0.0f;
#pragma unroll
      for (int s = 0; s < 4; ++s) {
        int p = (bi * 2 + (s >> 1)) * NS + bj * 2 + (s & 1);
        int idx = s_idx[p];
        int dx = s_dx[p];
        int dy = s_dy[p];
        float4 w = s_w[p];
        acc += w.x * f[idx] + w.y * f[idx + dx] + w.z * f[idx + dy] + w.w * f[idx + dy + dx];
      }
      o[bi * OW + bj] = acc * 0.25f;
    }
  }
}

extern "C" void kernel_launch(void* const* d_in, const int* in_sizes, int n_in,
                              void* d_out, int out_size, void* d_ws, size_t ws_size,
                              hipStream_t stream) {
  const float* feats = (const float*)d_in[0];  // (2,256,200,304) f32
  const float* rois = (const float*)d_in[1];   // (1000,6) f32
  float* out = (float*)d_out;                  // (1000,256,7,7) f32

  size_t need = (size_t)Bn * HWn * Cn * sizeof(float);  // ~124.6 MB
  if (ws_size >= need) {
    float* ft = (float*)d_ws;
    transpose2<<<dim3(HWn / TPX, Cn / TCH, Bn), 256, 0, stream>>>(feats, ft);
    roi_gather4<<<dim3(Nroi, Cn / 64), 256, 0, stream>>>(ft, rois, out);
  } else {
    roi_direct<<<Nroi, 256, 0, stream>>>(feats, rois, out);
  }
}

// Round 6
// 280.274 us; speedup vs baseline: 1.3673x; 1.0068x over previous
//
#include <hip/hip_runtime.h>
#include <math.h>

// Problem constants (from reference setup_inputs)
constexpr int Bn = 2, Cn = 256, Hn = 200, Wn = 304, Nroi = 1000;
constexpr int OH = 7, OW = 7, SRn = 2;
constexpr int NS = OH * SRn;   // 14 subsample rows/cols
constexpr int NP = NS * NS;    // 196 subsample positions per roi
constexpr int NBIN = OH * OW;  // 49
constexpr int HWn = Hn * Wn;   // 60800
constexpr float SCALE = 0.25f;

// ---------------------------------------------------------------------------
// Per-position sampling descriptor (matches JAX reference arithmetic, f32).
// ---------------------------------------------------------------------------
__device__ __forceinline__ void compute_desc(const float* __restrict__ r, int p,
                                             int& idx, int& dx, int& dyW,
                                             float4& w) {
  float cw = r[1] * SCALE - 0.5f;
  float ch = r[2] * SCALE - 0.5f;
  float rw = r[3] * SCALE;
  float rh = r[4] * SCALE;
  float theta = r[5] * 0.017453292519943295f;  // pi/180
  float cs = cosf(theta), sn = sinf(theta);
  float bin_h = rh * (1.0f / OH);
  float bin_w = rw * (1.0f / OW);
  int ki = p / NS;
  int kj = p - ki * NS;
  float ty = ((float)ki + 0.5f) * (1.0f / SRn);
  float tx = ((float)kj + 0.5f) * (1.0f / SRn);
  float yy = -0.5f * rh + ty * bin_h;
  float xx = -0.5f * rw + tx * bin_w;
  float y = yy * cs - xx * sn + ch;
  float x = yy * sn + xx * cs + cw;
  bool empty = (y < -1.0f) || (y > (float)Hn) || (x < -1.0f) || (x > (float)Wn);
  y = fmaxf(y, 0.0f);
  x = fmaxf(x, 0.0f);
  int yl = min(max((int)floorf(y), 0), Hn - 1);
  int xl = min(max((int)floorf(x), 0), Wn - 1);
  int yh = min(yl + 1, Hn - 1);
  int xh = min(xl + 1, Wn - 1);
  float ly = fminf(fmaxf(y - (float)yl, 0.0f), 1.0f);
  float lx = fminf(fmaxf(x - (float)xl, 0.0f), 1.0f);
  float hy = 1.0f - ly, hx = 1.0f - lx;
  if (empty) {
    w.x = w.y = w.z = w.w = 0.0f;
  } else {
    w.x = hy * hx;
    w.y = hy * lx;
    w.z = ly * hx;
    w.w = ly * lx;
  }
  idx = yl * Wn + xl;
  dx = xh - xl;
  dyW = (yh - yl) * Wn;
}

// ---------------------------------------------------------------------------
// Kernel 1: transpose feats (B,C,P) -> ft (B,P,C), 64px x 64ch tiles.
// (unchanged; remainder analysis shows it is not a significant cost)
// ---------------------------------------------------------------------------
constexpr int TPX = 64, TCH = 64, LP = TPX + 1;
__global__ __launch_bounds__(256) void transpose2(const float* __restrict__ feats,
                                                  float* __restrict__ ft) {
  __shared__ float tile[TCH * LP];
  int p0 = blockIdx.x * TPX;
  int c0 = blockIdx.y * TCH;
  int b = blockIdx.z;
  int t = threadIdx.x;
  int px4 = t & 15, ch = t >> 4;
#pragma unroll
  for (int i = 0; i < 4; ++i) {
    int c = ch + 16 * i;
    const float4 v = *(const float4*)(feats + ((size_t)b * Cn + c0 + c) * HWn + p0 + px4 * 4);
    tile[c * LP + px4 * 4 + 0] = v.x;
    tile[c * LP + px4 * 4 + 1] = v.y;
    tile[c * LP + px4 * 4 + 2] = v.z;
    tile[c * LP + px4 * 4 + 3] = v.w;
  }
  __syncthreads();
  int ch4 = t & 15, px = t >> 4;
#pragma unroll
  for (int i = 0; i < 4; ++i) {
    int p = px + 16 * i;
    float4 v;
    v.x = tile[(ch4 * 4 + 0) * LP + p];
    v.y = tile[(ch4 * 4 + 1) * LP + p];
    v.z = tile[(ch4 * 4 + 2) * LP + p];
    v.w = tile[(ch4 * 4 + 3) * LP + p];
    *(float4*)(ft + ((size_t)b * HWn + p0 + p) * Cn + c0 + ch4 * 4) = v;
  }
}

// ---------------------------------------------------------------------------
// Kernel 2 v5: float4 gather restructured for memory-level parallelism.
// R5 showed VGPR=36 -> compiler kept only ~4 loads in flight -> vmcnt-stall
// bound. Now each iteration is written loads-first (16 independent
// global_load_dwordx4 into an explicit array) then FMAs, 3 branch-free
// iterations (bins 0..47) + a 16-lane tail (bin 48), with
// __launch_bounds__(256,2) so the register allocator can hold the payload.
// Lane map unchanged: q=lane&15 channel quad, g=lane>>4 bin-in-pack.
// ---------------------------------------------------------------------------
__global__ __launch_bounds__(256, 2) void roi_gather5(const float* __restrict__ ft,
                                                      const float* __restrict__ rois,
                                                      float* __restrict__ out) {
  __shared__ int4 s_m[NP];   // {idxB, dxB, dyB, 0} byte offsets
  __shared__ float4 s_w[NP];
  __shared__ __align__(16) float s_out[64 * NBIN];  // 3136 floats = 784 float4
  int n = blockIdx.x;
  int cg = blockIdx.y;  // channel group 0..3 (64 channels each)
  const float* r = rois + (size_t)n * 6;
  int t = threadIdx.x;
  if (t < NP) {
    int idx, dx, dy;
    float4 w;
    compute_desc(r, t, idx, dx, dy, w);
    s_m[t] = make_int4(idx * (Cn * 4), dx * (Cn * 4), dy * (Cn * 4), 0);
    s_w[t] = w;
  }
  __syncthreads();
  int b = (int)r[0];
  int lane = t & 63;
  int wv = t >> 6;
  int q = lane & 15;   // channel quad
  int g = lane >> 4;   // bin group 0..3
  const char* fb = (const char*)(ft + (size_t)b * HWn * Cn + cg * 64) + q * 16;

#pragma unroll
  for (int it = 0; it < 3; ++it) {
    int bin = it * 16 + wv * 4 + g;  // 0..47, always valid
    int bi = bin / OW;
    int bj = bin - bi * OW;
    int p00 = (bi * 2) * NS + bj * 2;
    // --- descriptor reads (broadcast within 16-lane groups) ---
    int4 ma = s_m[p00];
    int4 mb = s_m[p00 + 1];
    int4 mc = s_m[p00 + NS];
    int4 md = s_m[p00 + NS + 1];
    float4 wa = s_w[p00];
    float4 wb = s_w[p00 + 1];
    float4 wc = s_w[p00 + NS];
    float4 wd = s_w[p00 + NS + 1];
    // --- 16 independent loads, issued before any use ---
    const char* Aa = fb + ma.x;
    const char* Ab = fb + mb.x;
    const char* Ac = fb + mc.x;
    const char* Ad = fb + md.x;
    float4 v[16];
    v[0]  = *(const float4*)(Aa);
    v[1]  = *(const float4*)(Aa + ma.y);
    v[2]  = *(const float4*)(Aa + ma.z);
    v[3]  = *(const float4*)(Aa + ma.z + ma.y);
    v[4]  = *(const float4*)(Ab);
    v[5]  = *(const float4*)(Ab + mb.y);
    v[6]  = *(const float4*)(Ab + mb.z);
    v[7]  = *(const float4*)(Ab + mb.z + mb.y);
    v[8]  = *(const float4*)(Ac);
    v[9]  = *(const float4*)(Ac + mc.y);
    v[10] = *(const float4*)(Ac + mc.z);
    v[11] = *(const float4*)(Ac + mc.z + mc.y);
    v[12] = *(const float4*)(Ad);
    v[13] = *(const float4*)(Ad + md.y);
    v[14] = *(const float4*)(Ad + md.z);
    v[15] = *(const float4*)(Ad + md.z + md.y);
    // --- combine ---
    float4 acc;
    acc.x = wa.x * v[0].x + wa.y * v[1].x + wa.z * v[2].x + wa.w * v[3].x;
    acc.y = wa.x * v[0].y + wa.y * v[1].y + wa.z * v[2].y + wa.w * v[3].y;
    acc.z = wa.x * v[0].z + wa.y * v[1].z + wa.z * v[2].z + wa.w * v[3].z;
    acc.w = wa.x * v[0].w + wa.y * v[1].w + wa.z * v[2].w + wa.w * v[3].w;
    acc.x += wb.x * v[4].x + wb.y * v[5].x + wb.z * v[6].x + wb.w * v[7].x;
    acc.y += wb.x * v[4].y + wb.y * v[5].y + wb.z * v[6].y + wb.w * v[7].y;
    acc.z += wb.x * v[4].z + wb.y * v[5].z + wb.z * v[6].z + wb.w * v[7].z;
    acc.w += wb.x * v[4].w + wb.y * v[5].w + wb.z * v[6].w + wb.w * v[7].w;
    acc.x += wc.x * v[8].x + wc.y * v[9].x + wc.z * v[10].x + wc.w * v[11].x;
    acc.y += wc.x * v[8].y + wc.y * v[9].y + wc.z * v[10].y + wc.w * v[11].y;
    acc.z += wc.x * v[8].z + wc.y * v[9].z + wc.z * v[10].z + wc.w * v[11].z;
    acc.w += wc.x * v[8].w + wc.y * v[9].w + wc.z * v[10].w + wc.w * v[11].w;
    acc.x += wd.x * v[12].x + wd.y * v[13].x + wd.z * v[14].x + wd.w * v[15].x;
    acc.y += wd.x * v[12].y + wd.y * v[13].y + wd.z * v[14].y + wd.w * v[15].y;
    acc.z += wd.x * v[12].z + wd.y * v[13].z + wd.z * v[14].z + wd.w * v[15].z;
    acc.w += wd.x * v[12].w + wd.y * v[13].w + wd.z * v[14].w + wd.w * v[15].w;
    s_out[(q * 4 + 0) * NBIN + bin] = acc.x * 0.25f;
    s_out[(q * 4 + 1) * NBIN + bin] = acc.y * 0.25f;
    s_out[(q * 4 + 2) * NBIN + bin] = acc.z * 0.25f;
    s_out[(q * 4 + 3) * NBIN + bin] = acc.w * 0.25f;
  }
  // --- tail: bin 48, handled by lanes t=0..15 (wv=0, g=0, q=t) ---
  if (t < 16) {
    constexpr int bin = 48;
    constexpr int p00 = 12 * NS + 12;
    int4 ma = s_m[p00], mb = s_m[p00 + 1], mc = s_m[p00 + NS], md = s_m[p00 + NS + 1];
    float4 wa = s_w[p00], wb = s_w[p00 + 1], wc = s_w[p00 + NS], wd = s_w[p00 + NS + 1];
    const char* Aa = fb + ma.x;
    const char* Ab = fb + mb.x;
    const char* Ac = fb + mc.x;
    const char* Ad = fb + md.x;
    float4 v[16];
    v[0]  = *(const float4*)(Aa);
    v[1]  = *(const float4*)(Aa + ma.y);
    v[2]  = *(const float4*)(Aa + ma.z);
    v[3]  = *(const float4*)(Aa + ma.z + ma.y);
    v[4]  = *(const float4*)(Ab);
    v[5]  = *(const float4*)(Ab + mb.y);
    v[6]  = *(const float4*)(Ab + mb.z);
    v[7]  = *(const float4*)(Ab + mb.z + mb.y);
    v[8]  = *(const float4*)(Ac);
    v[9]  = *(const float4*)(Ac + mc.y);
    v[10] = *(const float4*)(Ac + mc.z);
    v[11] = *(const float4*)(Ac + mc.z + mc.y);
    v[12] = *(const float4*)(Ad);
    v[13] = *(const float4*)(Ad + md.y);
    v[14] = *(const float4*)(Ad + md.z);
    v[15] = *(const float4*)(Ad + md.z + md.y);
    float4 acc;
    acc.x = wa.x * v[0].x + wa.y * v[1].x + wa.z * v[2].x + wa.w * v[3].x
          + wb.x * v[4].x + wb.y * v[5].x + wb.z * v[6].x + wb.w * v[7].x
          + wc.x * v[8].x + wc.y * v[9].x + wc.z * v[10].x + wc.w * v[11].x
          + wd.x * v[12].x + wd.y * v[13].x + wd.z * v[14].x + wd.w * v[15].x;
    acc.y = wa.x * v[0].y + wa.y * v[1].y + wa.z * v[2].y + wa.w * v[3].y
          + wb.x * v[4].y + wb.y * v[5].y + wb.z * v[6].y + wb.w * v[7].y
          + wc.x * v[8].y + wc.y * v[9].y + wc.z * v[10].y + wc.w * v[11].y
          + wd.x * v[12].y + wd.y * v[13].y + wd.z * v[14].y + wd.w * v[15].y;
    acc.z = wa.x * v[0].z + wa.y * v[1].z + wa.z * v[2].z + wa.w * v[3].z
          + wb.x * v[4].z + wb.y * v[5].z + wb.z * v[6].z + wb.w * v[7].z
          + wc.x * v[8].z + wc.y * v[9].z + wc.z * v[10].z + wc.w * v[11].z
          + wd.x * v[12].z + wd.y * v[13].z + wd.z * v[14].z + wd.w * v[15].z;
    acc.w = wa.x * v[0].w + wa.y * v[1].w + wa.z * v[2].w + wa.w * v[3].w
          + wb.x * v[4].w + wb.y * v[5].w + wb.z * v[6].w + wb.w * v[7].w
          + wc.x * v[8].w + wc.y * v[9].w + wc.z * v[10].w + wc.w * v[11].w
          + wd.x * v[12].w + wd.y * v[13].w + wd.z * v[14].w + wd.w * v[15].w;
    s_out[(q * 4 + 0) * NBIN + bin] = acc.x * 0.25f;
    s_out[(q * 4 + 1) * NBIN + bin] = acc.y * 0.25f;
    s_out[(q * 4 + 2) * NBIN + bin] = acc.z * 0.25f;
    s_out[(q * 4 + 3) * NBIN + bin] = acc.w * 0.25f;
  }
  __syncthreads();
  // Contiguous coalesced write-out: 64ch x 49bin = 3136 floats = 784 float4.
  const float4* s4 = (const float4*)s_out;
  float4* o4 = (float4*)(out + (size_t)n * Cn * NBIN + (size_t)cg * 64 * NBIN);
#pragma unroll
  for (int k = 0; k < 3; ++k) {
    o4[t + 256 * k] = s4[t + 256 * k];
  }
  if (t < 784 - 3 * 256) {
    o4[t + 256 * 3] = s4[t + 256 * 3];
  }
}

// ---------------------------------------------------------------------------
// Fallback (if workspace too small): direct gather from (B,C,H,W).
// ---------------------------------------------------------------------------
__global__ __launch_bounds__(256) void roi_direct(const float* __restrict__ feats,
                                                  const float* __restrict__ rois,
                                                  float* __restrict__ out) {
  __shared__ int s_idx[NP];
  __shared__ int s_dx[NP];
  __shared__ int s_dy[NP];
  __shared__ float4 s_w[NP];
  int n = blockIdx.x;
  const float* r = rois + (size_t)n * 6;
  int t = threadIdx.x;
  if (t < NP) {
    int idx, dx, dy;
    float4 w;
    compute_desc(r, t, idx, dx, dy, w);
    s_idx[t] = idx;
    s_dx[t] = dx;
    s_dy[t] = dy;
    s_w[t] = w;
  }
  __syncthreads();
  int b = (int)r[0];
  const float* f = feats + ((size_t)b * Cn + t) * HWn;
  float* o = out + ((size_t)n * Cn + t) * NBIN;
  for (int bi = 0; bi < OH; ++bi) {
    for (int bj = 0; bj < OW; ++bj) {
      float acc = 0.0f;
#pragma unroll
      for (int s = 0; s < 4; ++s) {
        int p = (bi * 2 + (s >> 1)) * NS + bj * 2 + (s & 1);
        int idx = s_idx[p];
        int dx = s_dx[p];
        int dy = s_dy[p];
        float4 w = s_w[p];
        acc += w.x * f[idx] + w.y * f[idx + dx] + w.z * f[idx + dy] + w.w * f[idx + dy + dx];
      }
      o[bi * OW + bj] = acc * 0.25f;
    }
  }
}

extern "C" void kernel_launch(void* const* d_in, const int* in_sizes, int n_in,
                              void* d_out, int out_size, void* d_ws, size_t ws_size,
                              hipStream_t stream) {
  const float* feats = (const float*)d_in[0];  // (2,256,200,304) f32
  const float* rois = (const float*)d_in[1];   // (1000,6) f32
  float* out = (float*)d_out;                  // (1000,256,7,7) f32

  size_t need = (size_t)Bn * HWn * Cn * sizeof(float);  // ~124.6 MB
  if (ws_size >= need) {
    float* ft = (float*)d_ws;
    transpose2<<<dim3(HWn / TPX, Cn / TCH, Bn), 256, 0, stream>>>(feats, ft);
    roi_gather5<<<dim3(Nroi, Cn / 64), 256, 0, stream>>>(ft, rois, out);
  } else {
    roi_direct<<<Nroi, 256, 0, stream>>>(feats, rois, out);
  }
}

// Round 7
// 241.392 us; speedup vs baseline: 1.5875x; 1.1611x over previous
//
#include <hip/hip_runtime.h>
#include <math.h>

// Problem constants (from reference setup_inputs)
constexpr int Bn = 2, Cn = 256, Hn = 200, Wn = 304, Nroi = 1000;
constexpr int OH = 7, OW = 7, SRn = 2;
constexpr int NS = OH * SRn;   // 14 subsample rows/cols
constexpr int NP = NS * NS;    // 196 subsample positions per roi
constexpr int NBIN = OH * OW;  // 49
constexpr int HWn = Hn * Wn;   // 60800
constexpr float SCALE = 0.25f;

// ---------------------------------------------------------------------------
// Per-position sampling descriptor (matches JAX reference arithmetic, f32).
// ---------------------------------------------------------------------------
__device__ __forceinline__ void compute_desc(const float* __restrict__ r, int p,
                                             int& idx, int& dx, int& dyW,
                                             float4& w) {
  float cw = r[1] * SCALE - 0.5f;
  float ch = r[2] * SCALE - 0.5f;
  float rw = r[3] * SCALE;
  float rh = r[4] * SCALE;
  float theta = r[5] * 0.017453292519943295f;  // pi/180
  float cs = cosf(theta), sn = sinf(theta);
  float bin_h = rh * (1.0f / OH);
  float bin_w = rw * (1.0f / OW);
  int ki = p / NS;
  int kj = p - ki * NS;
  float ty = ((float)ki + 0.5f) * (1.0f / SRn);
  float tx = ((float)kj + 0.5f) * (1.0f / SRn);
  float yy = -0.5f * rh + ty * bin_h;
  float xx = -0.5f * rw + tx * bin_w;
  float y = yy * cs - xx * sn + ch;
  float x = yy * sn + xx * cs + cw;
  bool empty = (y < -1.0f) || (y > (float)Hn) || (x < -1.0f) || (x > (float)Wn);
  y = fmaxf(y, 0.0f);
  x = fmaxf(x, 0.0f);
  int yl = min(max((int)floorf(y), 0), Hn - 1);
  int xl = min(max((int)floorf(x), 0), Wn - 1);
  int yh = min(yl + 1, Hn - 1);
  int xh = min(xl + 1, Wn - 1);
  float ly = fminf(fmaxf(y - (float)yl, 0.0f), 1.0f);
  float lx = fminf(fmaxf(x - (float)xl, 0.0f), 1.0f);
  float hy = 1.0f - ly, hx = 1.0f - lx;
  if (empty) {
    w.x = w.y = w.z = w.w = 0.0f;
  } else {
    w.x = hy * hx;
    w.y = hy * lx;
    w.z = ly * hx;
    w.w = ly * lx;
  }
  idx = yl * Wn + xl;
  dx = xh - xl;
  dyW = (yh - yl) * Wn;
}

__device__ __forceinline__ unsigned bf16rne(float f) {
  unsigned u = __float_as_uint(f);
  return (u + 0x7fffu + ((u >> 16) & 1u)) >> 16;
}
__device__ __forceinline__ unsigned bf16pack(float lo, float hi) {
  return bf16rne(lo) | (bf16rne(hi) << 16);
}

// ---------------------------------------------------------------------------
// Kernel 1 v3: transpose+downconvert feats (B,C,P) f32 -> ft (B,P,C) bf16.
// 64px x 64ch tiles; f32 staged in LDS; RNE convert on the write side.
// Read: 16B/lane coalesced. Write: 8 lanes x 16B = 128 B contiguous chunks,
// consecutive px at 512 B stride -> full 64 B lines covered.
// LDS banks both phases: {0,8,16,24}+small perm -> exactly 2-way = free.
// ---------------------------------------------------------------------------
constexpr int TPX = 64, TCH = 64, LP = TPX + 1;
__global__ __launch_bounds__(256) void transpose_bf16(const float* __restrict__ feats,
                                                      unsigned short* __restrict__ ft) {
  __shared__ float tile[TCH * LP];
  int p0 = blockIdx.x * TPX;
  int c0 = blockIdx.y * TCH;
  int b = blockIdx.z;
  int t = threadIdx.x;
  int px4 = t & 15, ch = t >> 4;
#pragma unroll
  for (int i = 0; i < 4; ++i) {
    int c = ch + 16 * i;
    const float4 v = *(const float4*)(feats + ((size_t)b * Cn + c0 + c) * HWn + p0 + px4 * 4);
    tile[c * LP + px4 * 4 + 0] = v.x;
    tile[c * LP + px4 * 4 + 1] = v.y;
    tile[c * LP + px4 * 4 + 2] = v.z;
    tile[c * LP + px4 * 4 + 3] = v.w;
  }
  __syncthreads();
  int o = t & 7;     // channel oct (8 ch = 16 B bf16)
  int px8 = t >> 3;  // 0..31
#pragma unroll
  for (int pass = 0; pass < 2; ++pass) {
    int p = px8 + 32 * pass;
    uint4 w4;
    w4.x = bf16pack(tile[(o * 8 + 0) * LP + p], tile[(o * 8 + 1) * LP + p]);
    w4.y = bf16pack(tile[(o * 8 + 2) * LP + p], tile[(o * 8 + 3) * LP + p]);
    w4.z = bf16pack(tile[(o * 8 + 4) * LP + p], tile[(o * 8 + 5) * LP + p]);
    w4.w = bf16pack(tile[(o * 8 + 6) * LP + p], tile[(o * 8 + 7) * LP + p]);
    *(uint4*)((char*)ft + (((size_t)b * HWn + p0 + p) * Cn + c0 + o * 8) * 2) = w4;
  }
}

// ---------------------------------------------------------------------------
// Kernel 2 v6: gather from bf16 ft, f32 accumulate.
// block = (roi, channel-group of 64); lane map: o = lane&7 (8 consecutive
// channels, one uint4 = 16 B), g = lane>>3 (8 bins per wave-iteration).
// Per corner-read a wave covers 8 bins x 128 B contiguous chunks; VMEM
// instructions per bin are HALF of the f32 version, and logical read bytes
// halve (784 -> 392 MB) -> attacks the L3-BW/queue bound seen in R6.
// bf16 -> f32 unpack is shift/mask (2 VALU per 2 channels).
// Output staged in LDS, then contiguous float4 write-out (WRITE stays 49 MB).
// ---------------------------------------------------------------------------
__global__ __launch_bounds__(256, 2) void roi_gather6(const unsigned short* __restrict__ ft,
                                                      const float* __restrict__ rois,
                                                      float* __restrict__ out) {
  __shared__ int4 s_m[NP];   // {idxB, dxB, dyB, 0} byte offsets into bf16 ft
  __shared__ float4 s_w[NP];
  __shared__ __align__(16) float s_out[64 * NBIN];  // 3136 floats = 784 float4
  int n = blockIdx.x;
  int cg = blockIdx.y;  // channel group 0..3 (64 channels each)
  const float* r = rois + (size_t)n * 6;
  int t = threadIdx.x;
  if (t < NP) {
    int idx, dx, dy;
    float4 w;
    compute_desc(r, t, idx, dx, dy, w);
    s_m[t] = make_int4(idx * (Cn * 2), dx * (Cn * 2), dy * (Cn * 2), 0);
    s_w[t] = w;
  }
  __syncthreads();
  int b = (int)r[0];
  int lane = t & 63;
  int wv = t >> 6;
  int o = lane & 7;   // channel oct
  int g = lane >> 3;  // bin group 0..7
  const char* fb = (const char*)ft + ((size_t)b * HWn * Cn + cg * 64 + o * 8) * 2;

#pragma unroll
  for (int it = 0; it < 2; ++it) {
    int bin = it * 32 + wv * 8 + g;
    if (bin < NBIN) {
      int bi = bin / OW;
      int bj = bin - bi * OW;
      int p00 = (bi * 2) * NS + bj * 2;
      float acc0 = 0.f, acc1 = 0.f, acc2 = 0.f, acc3 = 0.f;
      float acc4 = 0.f, acc5 = 0.f, acc6 = 0.f, acc7 = 0.f;
#pragma unroll
      for (int s = 0; s < 4; ++s) {
        int p = p00 + (s >> 1) * NS + (s & 1);
        int4 m = s_m[p];     // broadcast within 8-lane groups
        float4 w = s_w[p];
        const char* A = fb + m.x;
        // 4 corner loads issued back-to-back (independent)
        uint4 v1 = *(const uint4*)(A);
        uint4 v2 = *(const uint4*)(A + m.y);
        uint4 v3 = *(const uint4*)(A + m.z);
        uint4 v4 = *(const uint4*)(A + m.z + m.y);
#define ACC(vv, ww)                                                        \
        acc0 += (ww) * __uint_as_float((vv).x << 16);                      \
        acc1 += (ww) * __uint_as_float((vv).x & 0xffff0000u);              \
        acc2 += (ww) * __uint_as_float((vv).y << 16);                      \
        acc3 += (ww) * __uint_as_float((vv).y & 0xffff0000u);              \
        acc4 += (ww) * __uint_as_float((vv).z << 16);                      \
        acc5 += (ww) * __uint_as_float((vv).z & 0xffff0000u);              \
        acc6 += (ww) * __uint_as_float((vv).w << 16);                      \
        acc7 += (ww) * __uint_as_float((vv).w & 0xffff0000u);
        ACC(v1, w.x)
        ACC(v2, w.y)
        ACC(v3, w.z)
        ACC(v4, w.w)
#undef ACC
      }
      s_out[(o * 8 + 0) * NBIN + bin] = acc0 * 0.25f;
      s_out[(o * 8 + 1) * NBIN + bin] = acc1 * 0.25f;
      s_out[(o * 8 + 2) * NBIN + bin] = acc2 * 0.25f;
      s_out[(o * 8 + 3) * NBIN + bin] = acc3 * 0.25f;
      s_out[(o * 8 + 4) * NBIN + bin] = acc4 * 0.25f;
      s_out[(o * 8 + 5) * NBIN + bin] = acc5 * 0.25f;
      s_out[(o * 8 + 6) * NBIN + bin] = acc6 * 0.25f;
      s_out[(o * 8 + 7) * NBIN + bin] = acc7 * 0.25f;
    }
  }
  __syncthreads();
  // Contiguous coalesced write-out: 64ch x 49bin = 3136 floats = 784 float4.
  const float4* s4 = (const float4*)s_out;
  float4* o4 = (float4*)(out + (size_t)n * Cn * NBIN + (size_t)cg * 64 * NBIN);
#pragma unroll
  for (int k = 0; k < 3; ++k) {
    o4[t + 256 * k] = s4[t + 256 * k];
  }
  if (t < 784 - 3 * 256) {
    o4[t + 256 * 3] = s4[t + 256 * 3];
  }
}

// ---------------------------------------------------------------------------
// Fallback (if workspace too small): direct gather from (B,C,H,W), f32.
// ---------------------------------------------------------------------------
__global__ __launch_bounds__(256) void roi_direct(const float* __restrict__ feats,
                                                  const float* __restrict__ rois,
                                                  float* __restrict__ out) {
  __shared__ int s_idx[NP];
  __shared__ int s_dx[NP];
  __shared__ int s_dy[NP];
  __shared__ float4 s_w[NP];
  int n = blockIdx.x;
  const float* r = rois + (size_t)n * 6;
  int t = threadIdx.x;
  if (t < NP) {
    int idx, dx, dy;
    float4 w;
    compute_desc(r, t, idx, dx, dy, w);
    s_idx[t] = idx;
    s_dx[t] = dx;
    s_dy[t] = dy;
    s_w[t] = w;
  }
  __syncthreads();
  int b = (int)r[0];
  const float* f = feats + ((size_t)b * Cn + t) * HWn;
  float* o = out + ((size_t)n * Cn + t) * NBIN;
  for (int bi = 0; bi < OH; ++bi) {
    for (int bj = 0; bj < OW; ++bj) {
      float acc = 0.0f;
#pragma unroll
      for (int s = 0; s < 4; ++s) {
        int p = (bi * 2 + (s >> 1)) * NS + bj * 2 + (s & 1);
        int idx = s_idx[p];
        int dx = s_dx[p];
        int dy = s_dy[p];
        float4 w = s_w[p];
        acc += w.x * f[idx] + w.y * f[idx + dx] + w.z * f[idx + dy] + w.w * f[idx + dy + dx];
      }
      o[bi * OW + bj] = acc * 0.25f;
    }
  }
}

extern "C" void kernel_launch(void* const* d_in, const int* in_sizes, int n_in,
                              void* d_out, int out_size, void* d_ws, size_t ws_size,
                              hipStream_t stream) {
  const float* feats = (const float*)d_in[0];  // (2,256,200,304) f32
  const float* rois = (const float*)d_in[1];   // (1000,6) f32
  float* out = (float*)d_out;                  // (1000,256,7,7) f32

  size_t need = (size_t)Bn * HWn * Cn * sizeof(unsigned short);  // ~62.3 MB
  if (ws_size >= need) {
    unsigned short* ft = (unsigned short*)d_ws;
    transpose_bf16<<<dim3(HWn / TPX, Cn / TCH, Bn), 256, 0, stream>>>(feats, ft);
    roi_gather6<<<dim3(Nroi, Cn / 64), 256, 0, stream>>>(ft, rois, out);
  } else {
    roi_direct<<<Nroi, 256, 0, stream>>>(feats, rois, out);
  }
}